// Round 1
// baseline (1666.572 us; speedup 1.0000x reference)
//
#include <hip/hip_runtime.h>
#include <cstdint>
#include <cstddef>

// ---------------------------------------------------------------------------
// GEMM: Cout[N,M] = act( (ACCUM ? Cin : 0) + (HAS_BIAS ? bias : 0) + A[N,K] @ W[M,K]^T )
// Tile 64x64, BK=16, 256 threads, 4x4 accum per thread. fp32.
// ACT: 0=none, 1=relu, 2=leaky_relu(0.01)
// ---------------------------------------------------------------------------
template<int K, int ACT, bool ACCUM, bool HAS_BIAS>
__global__ __launch_bounds__(256) void gemm_act(
    const float* __restrict__ A, const float* __restrict__ W,
    const float* __restrict__ bias, const float* __restrict__ Cin,
    float* __restrict__ Cout, int N, int M)
{
    __shared__ float As[16][68];   // [k][row], padded to break bank conflicts
    __shared__ float Bs[16][68];   // [k][col]

    const int mt   = M >> 6;                // col tiles
    const int bx   = blockIdx.x % mt;
    const int by   = blockIdx.x / mt;
    const int row0 = by << 6;
    const int col0 = bx << 6;
    const int t  = threadIdx.x;
    const int tx = t & 15;                  // 0..15 -> output cols tx*4..+3
    const int ty = t >> 4;                  // 0..15 -> output rows ty*4..+3
    const int lr = t >> 2;                  // 0..63 staging row
    const int lc = (t & 3) << 2;            // 0,4,8,12 staging k-offset

    float acc[4][4];
#pragma unroll
    for (int i = 0; i < 4; i++)
#pragma unroll
        for (int j = 0; j < 4; j++) acc[i][j] = 0.f;

    const float* Aload = A + (size_t)(row0 + lr) * K + lc;
    const float* Wload = W + (size_t)(col0 + lr) * K + lc;

    for (int k0 = 0; k0 < K; k0 += 16) {
        float4 av = *(const float4*)(Aload + k0);
        float4 wv = *(const float4*)(Wload + k0);
        __syncthreads();
        As[lc + 0][lr] = av.x; As[lc + 1][lr] = av.y;
        As[lc + 2][lr] = av.z; As[lc + 3][lr] = av.w;
        Bs[lc + 0][lr] = wv.x; Bs[lc + 1][lr] = wv.y;
        Bs[lc + 2][lr] = wv.z; Bs[lc + 3][lr] = wv.w;
        __syncthreads();
#pragma unroll
        for (int kk = 0; kk < 16; kk++) {
            float4 a = *(const float4*)&As[kk][ty << 2];
            float4 b = *(const float4*)&Bs[kk][tx << 2];
            acc[0][0] += a.x * b.x; acc[0][1] += a.x * b.y;
            acc[0][2] += a.x * b.z; acc[0][3] += a.x * b.w;
            acc[1][0] += a.y * b.x; acc[1][1] += a.y * b.y;
            acc[1][2] += a.y * b.z; acc[1][3] += a.y * b.w;
            acc[2][0] += a.z * b.x; acc[2][1] += a.z * b.y;
            acc[2][2] += a.z * b.z; acc[2][3] += a.z * b.w;
            acc[3][0] += a.w * b.x; acc[3][1] += a.w * b.y;
            acc[3][2] += a.w * b.z; acc[3][3] += a.w * b.w;
        }
    }

    float bvals[4] = {0.f, 0.f, 0.f, 0.f};
    if (HAS_BIAS) {
#pragma unroll
        for (int j = 0; j < 4; j++) bvals[j] = bias[col0 + (tx << 2) + j];
    }

#pragma unroll
    for (int i = 0; i < 4; i++) {
        size_t off = (size_t)(row0 + (ty << 2) + i) * M + col0 + (tx << 2);
        float v[4];
#pragma unroll
        for (int j = 0; j < 4; j++) v[j] = acc[i][j] + bvals[j];
        if (ACCUM) {
            float4 cin = *(const float4*)&Cin[off];
            v[0] += cin.x; v[1] += cin.y; v[2] += cin.z; v[3] += cin.w;
        }
#pragma unroll
        for (int j = 0; j < 4; j++) {
            if (ACT == 1) v[j] = v[j] > 0.f ? v[j] : 0.f;
            if (ACT == 2) v[j] = v[j] > 0.f ? v[j] : 0.01f * v[j];
        }
        float4 o = make_float4(v[0], v[1], v[2], v[3]);
        *(float4*)&Cout[off] = o;
    }
}

// ---------------------------------------------------------------------------
// Per-edge segment-max: pooled[dst] = max(pooled[dst], y[src]).
// y >= 0 (post-relu), pooled initialized to 0, so signed-int atomicMax on the
// IEEE bit pattern is exact. 32 threads per edge, 4 feats each (float4 gather).
// ---------------------------------------------------------------------------
__global__ __launch_bounds__(256) void edge_max_kernel(
    const float* __restrict__ y, const int* __restrict__ src,
    const int* __restrict__ dst, int* __restrict__ pooled_i, int E)
{
    int tid = blockIdx.x * blockDim.x + threadIdx.x;
    int e = tid >> 5;
    if (e >= E) return;
    int c = (tid & 31) << 2;
    int s = src[e];
    int d = dst[e];
    float4 v = *(const float4*)&y[(size_t)s * 128 + c];
    int base = d * 128 + c;
    atomicMax(&pooled_i[base + 0], __float_as_int(v.x));
    atomicMax(&pooled_i[base + 1], __float_as_int(v.y));
    atomicMax(&pooled_i[base + 2], __float_as_int(v.z));
    atomicMax(&pooled_i[base + 3], __float_as_int(v.w));
}

// ---------------------------------------------------------------------------
// Head: out[N,16] = sigmoid(H[N,256] @ W2[16,256]^T + b2). 16 rows per block.
// ---------------------------------------------------------------------------
__global__ __launch_bounds__(256) void head_kernel(
    const float* __restrict__ H, const float* __restrict__ W2,
    const float* __restrict__ b2, float* __restrict__ out, int N)
{
    __shared__ float Wsh[16][257];
    __shared__ float Hsh[16][257];
    const int row0 = blockIdx.x << 4;
    const int t = threadIdx.x;

    for (int i = t; i < 16 * 64; i += 256) {
        int r = i >> 6, c = (i & 63) << 2;
        float4 w = *(const float4*)&W2[r * 256 + c];
        Wsh[r][c + 0] = w.x; Wsh[r][c + 1] = w.y; Wsh[r][c + 2] = w.z; Wsh[r][c + 3] = w.w;
        float4 h = *(const float4*)&H[(size_t)(row0 + r) * 256 + c];
        Hsh[r][c + 0] = h.x; Hsh[r][c + 1] = h.y; Hsh[r][c + 2] = h.z; Hsh[r][c + 3] = h.w;
    }
    __syncthreads();

    int r = t >> 4;       // 0..15
    int c = t & 15;       // 0..15
    float s = b2[c];
#pragma unroll 8
    for (int k = 0; k < 256; k++) s += Hsh[r][k] * Wsh[c][k];
    out[(size_t)(row0 + r) * 16 + c] = 1.f / (1.f + expf(-s));
}

// ---------------------------------------------------------------------------
extern "C" void kernel_launch(void* const* d_in, const int* in_sizes, int n_in,
                              void* d_out, int out_size, void* d_ws, size_t ws_size,
                              hipStream_t stream)
{
    const float* x  = (const float*)d_in[0];
    const float* Wp = (const float*)d_in[1];
    const float* bp = (const float*)d_in[2];
    const float* Ws = (const float*)d_in[3];
    const float* Wn = (const float*)d_in[4];
    const float* bn = (const float*)d_in[5];
    const float* W1 = (const float*)d_in[6];
    const float* b1 = (const float*)d_in[7];
    const float* W2 = (const float*)d_in[8];
    const float* b2 = (const float*)d_in[9];
    const int* src  = (const int*)d_in[10];
    const int* dst  = (const int*)d_in[11];
    float* out = (float*)d_out;

    const int N = in_sizes[0] / 128;   // 65536
    const int E = in_sizes[10];        // 1048576

    float* bufA = (float*)d_ws;                    // y, then h      [N,128]
    float* bufB = bufA + (size_t)N * 128;          // pooled         [N,128]
    float* bufC = bufB + (size_t)N * 128;          // tmp/h2         [N,256]

    dim3 blk(256);
    const int grid_m128 = (N / 64) * (128 / 64);   // 2048
    const int grid_m256 = (N / 64) * (256 / 64);   // 4096

    // K1: y = relu(x @ Wp^T + bp)   -> bufA
    gemm_act<128, 1, false, true><<<grid_m128, blk, 0, stream>>>(
        x, Wp, bp, nullptr, bufA, N, 128);

    // K4a: tmp = x @ Ws^T + bn      -> bufC (independent of pooling)
    gemm_act<128, 0, false, true><<<grid_m128, blk, 0, stream>>>(
        x, Ws, bn, nullptr, bufC, N, 128);

    // pooled = 0
    hipMemsetAsync(bufB, 0, (size_t)N * 128 * sizeof(float), stream);

    // K3: pooled[dst] = max(pooled[dst], y[src])   (int-atomicMax, y >= 0)
    int edge_threads_blocks = (E * 32 + 255) / 256;
    edge_max_kernel<<<edge_threads_blocks, blk, 0, stream>>>(
        bufA, src, dst, (int*)bufB, E);

    // K4b: h = leaky_relu(tmp + pooled @ Wn^T)     -> bufA
    gemm_act<128, 2, true, false><<<grid_m128, blk, 0, stream>>>(
        bufB, Wn, nullptr, bufC, bufA, N, 128);

    // K5: h2 = leaky_relu(h @ W1^T + b1)           -> bufC
    gemm_act<128, 2, false, true><<<grid_m256, blk, 0, stream>>>(
        bufA, W1, b1, nullptr, bufC, N, 256);

    // K6: out = sigmoid(h2 @ W2^T + b2)
    head_kernel<<<N / 16, blk, 0, stream>>>(bufC, W2, b2, out, N);
}

// Round 2
// 532.567 us; speedup vs baseline: 3.1293x; 3.1293x over previous
//
#include <hip/hip_runtime.h>
#include <cstdint>
#include <cstddef>

// ---------------------------------------------------------------------------
// GEMM: Cout[N,M] = act( (ACCUM ? Cin : 0) + (HAS_BIAS ? bias : 0) + A[N,K] @ W[M,K]^T )
// Tile 64x64, BK=16, 256 threads, 4x4 accum per thread. fp32.
// ACT: 0=none, 1=relu, 2=leaky_relu(0.01)
// ---------------------------------------------------------------------------
template<int K, int ACT, bool ACCUM, bool HAS_BIAS>
__global__ __launch_bounds__(256) void gemm_act(
    const float* __restrict__ A, const float* __restrict__ W,
    const float* __restrict__ bias, const float* __restrict__ Cin,
    float* __restrict__ Cout, int N, int M)
{
    __shared__ float As[16][68];   // [k][row], padded to break bank conflicts
    __shared__ float Bs[16][68];   // [k][col]

    const int mt   = M >> 6;                // col tiles
    const int bx   = blockIdx.x % mt;
    const int by   = blockIdx.x / mt;
    const int row0 = by << 6;
    const int col0 = bx << 6;
    const int t  = threadIdx.x;
    const int tx = t & 15;                  // 0..15 -> output cols tx*4..+3
    const int ty = t >> 4;                  // 0..15 -> output rows ty*4..+3
    const int lr = t >> 2;                  // 0..63 staging row
    const int lc = (t & 3) << 2;            // 0,4,8,12 staging k-offset

    float acc[4][4];
#pragma unroll
    for (int i = 0; i < 4; i++)
#pragma unroll
        for (int j = 0; j < 4; j++) acc[i][j] = 0.f;

    const float* Aload = A + (size_t)(row0 + lr) * K + lc;
    const float* Wload = W + (size_t)(col0 + lr) * K + lc;

    for (int k0 = 0; k0 < K; k0 += 16) {
        float4 av = *(const float4*)(Aload + k0);
        float4 wv = *(const float4*)(Wload + k0);
        __syncthreads();
        As[lc + 0][lr] = av.x; As[lc + 1][lr] = av.y;
        As[lc + 2][lr] = av.z; As[lc + 3][lr] = av.w;
        Bs[lc + 0][lr] = wv.x; Bs[lc + 1][lr] = wv.y;
        Bs[lc + 2][lr] = wv.z; Bs[lc + 3][lr] = wv.w;
        __syncthreads();
#pragma unroll
        for (int kk = 0; kk < 16; kk++) {
            float4 a = *(const float4*)&As[kk][ty << 2];
            float4 b = *(const float4*)&Bs[kk][tx << 2];
            acc[0][0] += a.x * b.x; acc[0][1] += a.x * b.y;
            acc[0][2] += a.x * b.z; acc[0][3] += a.x * b.w;
            acc[1][0] += a.y * b.x; acc[1][1] += a.y * b.y;
            acc[1][2] += a.y * b.z; acc[1][3] += a.y * b.w;
            acc[2][0] += a.z * b.x; acc[2][1] += a.z * b.y;
            acc[2][2] += a.z * b.z; acc[2][3] += a.z * b.w;
            acc[3][0] += a.w * b.x; acc[3][1] += a.w * b.y;
            acc[3][2] += a.w * b.z; acc[3][3] += a.w * b.w;
        }
    }

    float bvals[4] = {0.f, 0.f, 0.f, 0.f};
    if (HAS_BIAS) {
#pragma unroll
        for (int j = 0; j < 4; j++) bvals[j] = bias[col0 + (tx << 2) + j];
    }

#pragma unroll
    for (int i = 0; i < 4; i++) {
        size_t off = (size_t)(row0 + (ty << 2) + i) * M + col0 + (tx << 2);
        float v[4];
#pragma unroll
        for (int j = 0; j < 4; j++) v[j] = acc[i][j] + bvals[j];
        if (ACCUM) {
            float4 cin = *(const float4*)&Cin[off];
            v[0] += cin.x; v[1] += cin.y; v[2] += cin.z; v[3] += cin.w;
        }
#pragma unroll
        for (int j = 0; j < 4; j++) {
            if (ACT == 1) v[j] = v[j] > 0.f ? v[j] : 0.f;
            if (ACT == 2) v[j] = v[j] > 0.f ? v[j] : 0.01f * v[j];
        }
        float4 o = make_float4(v[0], v[1], v[2], v[3]);
        *(float4*)&Cout[off] = o;
    }
}

// ---------------------------------------------------------------------------
// CSR build: histogram -> scan -> scatter. All on-device, per call.
// ---------------------------------------------------------------------------
__global__ __launch_bounds__(256) void hist_kernel(
    const int* __restrict__ dst, int* __restrict__ cnt, int E)
{
    int e = blockIdx.x * blockDim.x + threadIdx.x;
    if (e < E) atomicAdd(&cnt[dst[e]], 1);
}

// Single block, 1024 threads, N = 65536 (64 counts per thread).
__global__ __launch_bounds__(1024) void scan_kernel(
    const int* __restrict__ cnt, int* __restrict__ off,
    int* __restrict__ cur, int N)
{
    __shared__ int sums[1024];
    const int t = threadIdx.x;
    const int base = t * 64;
    int s = 0;
    for (int i = 0; i < 64; i++) s += cnt[base + i];
    sums[t] = s;
    __syncthreads();
    // Hillis-Steele inclusive scan
    for (int d = 1; d < 1024; d <<= 1) {
        int add = (t >= d) ? sums[t - d] : 0;
        __syncthreads();
        sums[t] += add;
        __syncthreads();
    }
    int running = (t == 0) ? 0 : sums[t - 1];   // exclusive base for my chunk
    for (int i = 0; i < 64; i++) {
        off[base + i] = running;
        cur[base + i] = running;
        running += cnt[base + i];
    }
    if (t == 1023) off[N] = sums[1023];
}

__global__ __launch_bounds__(256) void scatter_kernel(
    const int* __restrict__ src, const int* __restrict__ dst,
    int* __restrict__ cur, int* __restrict__ esrc, int E)
{
    int e = blockIdx.x * blockDim.x + threadIdx.x;
    if (e < E) {
        int pos = atomicAdd(&cur[dst[e]], 1);
        esrc[pos] = src[e];
    }
}

// ---------------------------------------------------------------------------
// Segment-max via CSR, no atomics. One wave (64 lanes) per dst node; lane
// handles 2 feats (float2). Edge indices preloaded 64-at-a-time and shuffled.
// pooled init 0 covers isolated nodes (y >= 0 post-relu).
// ---------------------------------------------------------------------------
__global__ __launch_bounds__(256) void pool_kernel(
    const float* __restrict__ y, const int* __restrict__ off,
    const int* __restrict__ esrc, float* __restrict__ pooled, int N)
{
    const int node = blockIdx.x * 4 + (threadIdx.x >> 6);
    const int lane = threadIdx.x & 63;
    const int beg = off[node];
    const int end = off[node + 1];
    float2 acc = make_float2(0.f, 0.f);
    for (int j0 = beg; j0 < end; j0 += 64) {
        int myidx = (j0 + lane < end) ? esrc[j0 + lane] : 0;
        int cnt = min(64, end - j0);
        for (int k = 0; k < cnt; k++) {
            int s = __shfl(myidx, k);
            float2 v = *(const float2*)&y[(size_t)s * 128 + lane * 2];
            acc.x = fmaxf(acc.x, v.x);
            acc.y = fmaxf(acc.y, v.y);
        }
    }
    *(float2*)&pooled[(size_t)node * 128 + lane * 2] = acc;
}

// ---------------------------------------------------------------------------
// Head: out[N,16] = sigmoid(H[N,256] @ W2[16,256]^T + b2). 16 rows per block.
// ---------------------------------------------------------------------------
__global__ __launch_bounds__(256) void head_kernel(
    const float* __restrict__ H, const float* __restrict__ W2,
    const float* __restrict__ b2, float* __restrict__ out, int N)
{
    __shared__ float Wsh[16][257];
    __shared__ float Hsh[16][257];
    const int row0 = blockIdx.x << 4;
    const int t = threadIdx.x;

    for (int i = t; i < 16 * 64; i += 256) {
        int r = i >> 6, c = (i & 63) << 2;
        float4 w = *(const float4*)&W2[r * 256 + c];
        Wsh[r][c + 0] = w.x; Wsh[r][c + 1] = w.y; Wsh[r][c + 2] = w.z; Wsh[r][c + 3] = w.w;
        float4 h = *(const float4*)&H[(size_t)(row0 + r) * 256 + c];
        Hsh[r][c + 0] = h.x; Hsh[r][c + 1] = h.y; Hsh[r][c + 2] = h.z; Hsh[r][c + 3] = h.w;
    }
    __syncthreads();

    int r = t >> 4;       // 0..15
    int c = t & 15;       // 0..15
    float s = b2[c];
#pragma unroll 8
    for (int k = 0; k < 256; k++) s += Hsh[r][k] * Wsh[c][k];
    out[(size_t)(row0 + r) * 16 + c] = 1.f / (1.f + expf(-s));
}

// ---------------------------------------------------------------------------
extern "C" void kernel_launch(void* const* d_in, const int* in_sizes, int n_in,
                              void* d_out, int out_size, void* d_ws, size_t ws_size,
                              hipStream_t stream)
{
    const float* x  = (const float*)d_in[0];
    const float* Wp = (const float*)d_in[1];
    const float* bp = (const float*)d_in[2];
    const float* Ws = (const float*)d_in[3];
    const float* Wn = (const float*)d_in[4];
    const float* bn = (const float*)d_in[5];
    const float* W1 = (const float*)d_in[6];
    const float* b1 = (const float*)d_in[7];
    const float* W2 = (const float*)d_in[8];
    const float* b2 = (const float*)d_in[9];
    const int* src  = (const int*)d_in[10];
    const int* dst  = (const int*)d_in[11];
    float* out = (float*)d_out;

    const int N = in_sizes[0] / 128;   // 65536
    const int E = in_sizes[10];        // 1048576

    // ws layout (total 128 MiB):
    //   [  0 ..  32M) bufA : y, later h        [N,128]
    //   [ 32M..  64M) bufB : pooled            [N,128]
    //   [ 64M.. 128M) bufC : tmp [N,128] then h2 [N,256]
    //   CSR arrays live at [96M..101M) — inside bufC's upper half, which is
    //   dead until K5 writes h2 (after pooling completes).
    float* bufA = (float*)d_ws;
    float* bufB = bufA + (size_t)N * 128;
    float* bufC = bufB + (size_t)N * 128;

    char* csr_base = (char*)d_ws + (size_t)96 * 1024 * 1024;
    int* csr_cnt = (int*)csr_base;          // N
    int* csr_off = csr_cnt + N;             // N+1
    int* csr_cur = csr_off + N + 1;         // N
    int* esrc    = csr_cur + N;             // E

    dim3 blk(256);
    const int grid_m128 = (N / 64) * (128 / 64);   // 2048
    const int grid_m256 = (N / 64) * (256 / 64);   // 4096

    // --- CSR build (depends only on src/dst) ---
    hipMemsetAsync(csr_cnt, 0, (size_t)N * sizeof(int), stream);
    hist_kernel<<<(E + 255) / 256, blk, 0, stream>>>(dst, csr_cnt, E);
    scan_kernel<<<1, 1024, 0, stream>>>(csr_cnt, csr_off, csr_cur, N);
    scatter_kernel<<<(E + 255) / 256, blk, 0, stream>>>(src, dst, csr_cur, esrc, E);

    // K1: y = relu(x @ Wp^T + bp)   -> bufA
    gemm_act<128, 1, false, true><<<grid_m128, blk, 0, stream>>>(
        x, Wp, bp, nullptr, bufA, N, 128);

    // K4a: tmp = x @ Ws^T + bn      -> bufC (independent of pooling)
    gemm_act<128, 0, false, true><<<grid_m128, blk, 0, stream>>>(
        x, Ws, bn, nullptr, bufC, N, 128);

    // pool: pooled[n] = max over edges of y[src]  (no atomics)
    pool_kernel<<<N / 4, blk, 0, stream>>>(bufA, csr_off, esrc, bufB, N);

    // K4b: h = leaky_relu(tmp + pooled @ Wn^T)     -> bufA
    gemm_act<128, 2, true, false><<<grid_m128, blk, 0, stream>>>(
        bufB, Wn, nullptr, bufC, bufA, N, 128);

    // K5: h2 = leaky_relu(h @ W1^T + b1)           -> bufC
    gemm_act<128, 2, false, true><<<grid_m256, blk, 0, stream>>>(
        bufA, W1, b1, nullptr, bufC, N, 256);

    // K6: out = sigmoid(h2 @ W2^T + b2)
    head_kernel<<<N / 16, blk, 0, stream>>>(bufC, W2, b2, out, N);
}

// Round 3
// 388.464 us; speedup vs baseline: 4.2902x; 1.3710x over previous
//
#include <hip/hip_runtime.h>
#include <cstdint>
#include <cstddef>

typedef __attribute__((ext_vector_type(8))) __bf16 bf16x8;
typedef __attribute__((ext_vector_type(4))) float f32x4;

static __device__ __forceinline__ unsigned short f2b(float f) {
    union { float f; unsigned int u; } v; v.f = f;
    unsigned int u = v.u;
    unsigned int r = (u + 0x7fffu + ((u >> 16) & 1u)) >> 16;  // RNE
    return (unsigned short)r;
}

// ---------------------------------------------------------------------------
// MFMA GEMM: C[M,Ncols](bf16) = act(A[M,K](bf16, stride strideA) @ W[Ncols,K](bf16)^T + bias)
// Block 256 thr = 4 waves (2x2), wave does 64x64 via 4x4 tiles of 16x16x32.
// Fragment layouts (verified m89/m91/m120): A: m=lane&15, k=quad*8+j;
// B from row-major W: n=lane&15, k=quad*8+j; C/D: col=lane&15, row=quad*4+reg.
// ACT: 1=relu, 2=leaky_relu(0.01)
// ---------------------------------------------------------------------------
template<int K, int ACT>
__global__ __launch_bounds__(256) void mfma_gemm(
    const unsigned short* __restrict__ A, int strideA,
    const unsigned short* __restrict__ W,
    const float* __restrict__ bias,
    unsigned short* __restrict__ C, int Ncols)
{
    const int nt = Ncols >> 7;
    const int bm = (int)blockIdx.x / nt, bn = (int)blockIdx.x % nt;
    const int w  = threadIdx.x >> 6;
    const int wm = w & 1, wn = w >> 1;
    const int l  = threadIdx.x & 63;
    const int lr = l & 15, quad = l >> 4;
    const int m0 = bm * 128 + wm * 64;
    const int n0 = bn * 128 + wn * 64;

    f32x4 acc[4][4];
#pragma unroll
    for (int i = 0; i < 4; i++)
#pragma unroll
        for (int j = 0; j < 4; j++) acc[i][j] = (f32x4){0.f, 0.f, 0.f, 0.f};

    const unsigned short* Ap = A + (size_t)(m0 + lr) * strideA + quad * 8;
    const unsigned short* Bp = W + (size_t)(n0 + lr) * K + quad * 8;

    for (int ks = 0; ks < K / 32; ks++) {
        bf16x8 af[4], bf[4];
#pragma unroll
        for (int i = 0; i < 4; i++)
            af[i] = *(const bf16x8*)(Ap + (size_t)i * 16 * strideA + ks * 32);
#pragma unroll
        for (int i = 0; i < 4; i++)
            bf[i] = *(const bf16x8*)(Bp + (size_t)i * 16 * K + ks * 32);
#pragma unroll
        for (int mi = 0; mi < 4; mi++)
#pragma unroll
            for (int ni = 0; ni < 4; ni++)
                acc[mi][ni] = __builtin_amdgcn_mfma_f32_16x16x32_bf16(
                    af[mi], bf[ni], acc[mi][ni], 0, 0, 0);
    }

#pragma unroll
    for (int ni = 0; ni < 4; ni++) {
        const int col = n0 + ni * 16 + lr;
        const float bv = bias[col];
#pragma unroll
        for (int mi = 0; mi < 4; mi++) {
#pragma unroll
            for (int r = 0; r < 4; r++) {
                const int row = m0 + mi * 16 + quad * 4 + r;
                float v = acc[mi][ni][r] + bv;
                if (ACT == 1) v = v > 0.f ? v : 0.f;
                if (ACT == 2) v = v > 0.f ? v : 0.01f * v;
                C[(size_t)row * Ncols + col] = f2b(v);
            }
        }
    }
}

// ---------------------------------------------------------------------------
// Head: out[N,16](fp32) = sigmoid(H[N,256](bf16) @ W2[16,256](bf16)^T + b2).
// One wave per 16 rows, single 16x16 accumulator, K=256 in 8 MFMA steps.
// ---------------------------------------------------------------------------
__global__ __launch_bounds__(256) void head_mfma(
    const unsigned short* __restrict__ H, const unsigned short* __restrict__ W2b,
    const float* __restrict__ b2, float* __restrict__ out)
{
    const int wave = (int)(blockIdx.x * 4) + (threadIdx.x >> 6);
    const int l = threadIdx.x & 63;
    const int lr = l & 15, quad = l >> 4;
    const int m0 = wave * 16;
    f32x4 acc = (f32x4){0.f, 0.f, 0.f, 0.f};
#pragma unroll
    for (int ks = 0; ks < 8; ks++) {
        bf16x8 a = *(const bf16x8*)(H + (size_t)(m0 + lr) * 256 + ks * 32 + quad * 8);
        bf16x8 b = *(const bf16x8*)(W2b + (size_t)lr * 256 + ks * 32 + quad * 8);
        acc = __builtin_amdgcn_mfma_f32_16x16x32_bf16(a, b, acc, 0, 0, 0);
    }
    const float bv = b2[lr];
#pragma unroll
    for (int r = 0; r < 4; r++) {
        const int row = m0 + quad * 4 + r;
        float v = acc[r] + bv;
        out[(size_t)row * 16 + lr] = 1.f / (1.f + __expf(-v));
    }
}

// ---------------------------------------------------------------------------
// Conversions
// ---------------------------------------------------------------------------
__global__ __launch_bounds__(256) void conv_x_kernel(
    const float* __restrict__ x, unsigned short* __restrict__ bufX, int total)
{
    int t = blockIdx.x * 256 + threadIdx.x;
    if (t >= total) return;
    int row = t >> 5, seg = t & 31;
    float4 v = *(const float4*)(x + (size_t)row * 128 + seg * 4);
    ushort4 o;
    o.x = f2b(v.x); o.y = f2b(v.y); o.z = f2b(v.z); o.w = f2b(v.w);
    *(ushort4*)(bufX + (size_t)row * 256 + seg * 4) = o;
}

__global__ __launch_bounds__(256) void conv_w_kernel(
    const float* __restrict__ Wp, const float* __restrict__ Ws,
    const float* __restrict__ Wn, const float* __restrict__ W1,
    const float* __restrict__ W2,
    unsigned short* __restrict__ Wp_b, unsigned short* __restrict__ Wcat,
    unsigned short* __restrict__ W1_b, unsigned short* __restrict__ W2_b)
{
    int i = blockIdx.x * 256 + threadIdx.x;
    if (i < 16384) {
        Wp_b[i] = f2b(Wp[i]);
    } else if (i < 49152) {
        int j = i - 16384; int o = j >> 8, k = j & 255;
        Wcat[j] = f2b(k < 128 ? Ws[o * 128 + k] : Wn[o * 128 + (k - 128)]);
    } else if (i < 81920) {
        W1_b[i - 49152] = f2b(W1[i - 49152]);
    } else if (i < 86016) {
        W2_b[i - 81920] = f2b(W2[i - 81920]);
    }
}

// ---------------------------------------------------------------------------
// CSR build: histogram -> scan -> scatter.
// ---------------------------------------------------------------------------
__global__ __launch_bounds__(256) void hist_kernel(
    const int* __restrict__ dst, int* __restrict__ cnt, int E)
{
    int e = blockIdx.x * blockDim.x + threadIdx.x;
    if (e < E) atomicAdd(&cnt[dst[e]], 1);
}

__global__ __launch_bounds__(1024) void scan_kernel(
    const int* __restrict__ cnt, int* __restrict__ off,
    int* __restrict__ cur, int N)
{
    __shared__ int sums[1024];
    const int t = threadIdx.x;
    const int base = t * 64;
    int s = 0;
    for (int i = 0; i < 64; i++) s += cnt[base + i];
    sums[t] = s;
    __syncthreads();
    for (int d = 1; d < 1024; d <<= 1) {
        int add = (t >= d) ? sums[t - d] : 0;
        __syncthreads();
        sums[t] += add;
        __syncthreads();
    }
    int running = (t == 0) ? 0 : sums[t - 1];
    for (int i = 0; i < 64; i++) {
        off[base + i] = running;
        cur[base + i] = running;
        running += cnt[base + i];
    }
    if (t == 1023) off[N] = sums[1023];
}

__global__ __launch_bounds__(256) void scatter_kernel(
    const int* __restrict__ src, const int* __restrict__ dst,
    int* __restrict__ cur, int* __restrict__ esrc, int E)
{
    int e = blockIdx.x * blockDim.x + threadIdx.x;
    if (e < E) {
        int pos = atomicAdd(&cur[dst[e]], 1);
        esrc[pos] = src[e];
    }
}

// ---------------------------------------------------------------------------
// Segment-max on bf16 y (no atomics): one wave per node, lane owns 2 feats.
// Writes pooled into cols 128:256 of bufX (the concat GEMM input).
// ---------------------------------------------------------------------------
__global__ __launch_bounds__(256) void pool_kernel(
    const unsigned int* __restrict__ y, const int* __restrict__ off,
    const int* __restrict__ esrc, unsigned short* __restrict__ bufX)
{
    const int node = blockIdx.x * 4 + (threadIdx.x >> 6);
    const int lane = threadIdx.x & 63;
    const int beg = off[node];
    const int end = off[node + 1];
    float ax = 0.f, ay = 0.f;
    for (int j0 = beg; j0 < end; j0 += 64) {
        int myidx = (j0 + lane < end) ? esrc[j0 + lane] : 0;
        int cnt = min(64, end - j0);
        for (int k = 0; k < cnt; k++) {
            int s = __shfl(myidx, k);
            unsigned int v = y[(size_t)s * 64 + lane];
            ax = fmaxf(ax, __uint_as_float(v << 16));
            ay = fmaxf(ay, __uint_as_float(v & 0xffff0000u));
        }
    }
    unsigned int packed = (__float_as_uint(ax) >> 16) | (__float_as_uint(ay) & 0xffff0000u);
    *(unsigned int*)(bufX + (size_t)node * 256 + 128 + lane * 2) = packed;
}

// ---------------------------------------------------------------------------
extern "C" void kernel_launch(void* const* d_in, const int* in_sizes, int n_in,
                              void* d_out, int out_size, void* d_ws, size_t ws_size,
                              hipStream_t stream)
{
    const float* x  = (const float*)d_in[0];
    const float* Wp = (const float*)d_in[1];
    const float* bp = (const float*)d_in[2];
    const float* Ws = (const float*)d_in[3];
    const float* Wn = (const float*)d_in[4];
    const float* bn = (const float*)d_in[5];
    const float* W1 = (const float*)d_in[6];
    const float* b1 = (const float*)d_in[7];
    const float* W2 = (const float*)d_in[8];
    const float* b2 = (const float*)d_in[9];
    const int* src  = (const int*)d_in[10];
    const int* dst  = (const int*)d_in[11];
    float* out = (float*)d_out;

    const int N = in_sizes[0] / 128;   // 65536
    const int E = in_sizes[10];        // 1048576

    // ws layout:
    //   [ 0,32M)  bufX  : [N,256] bf16 — cols 0:128 = xb, cols 128:256 = pooled
    //   [32M,48M) y     : [N,128] bf16
    //   [48M,64M) hbuf  : [N,128] bf16
    //   [64M,96M) h2    : [N,256] bf16
    //   [96M,..)  weights bf16, then CSR ints
    unsigned short* bufX = (unsigned short*)d_ws;
    unsigned short* y    = (unsigned short*)((char*)d_ws + (size_t)32 * 1024 * 1024);
    unsigned short* hbuf = (unsigned short*)((char*)d_ws + (size_t)48 * 1024 * 1024);
    unsigned short* h2   = (unsigned short*)((char*)d_ws + (size_t)64 * 1024 * 1024);

    unsigned short* Wp_b = (unsigned short*)((char*)d_ws + (size_t)96 * 1024 * 1024);
    unsigned short* Wcat = Wp_b + 16384;     // 128 x 256
    unsigned short* W1_b = Wcat + 32768;     // 256 x 128
    unsigned short* W2_b = W1_b + 32768;     // 16 x 256
    int* csr_cnt = (int*)(W2_b + 4096);
    int* csr_off = csr_cnt + N;
    int* csr_cur = csr_off + N + 1;
    int* esrc    = csr_cur + N;

    dim3 blk(256);

    // conversions (independent)
    conv_w_kernel<<<(86016 + 255) / 256, blk, 0, stream>>>(
        Wp, Ws, Wn, W1, W2, Wp_b, Wcat, W1_b, W2_b);
    conv_x_kernel<<<(N * 32 + 255) / 256, blk, 0, stream>>>(x, bufX, N * 32);

    // CSR build
    hipMemsetAsync(csr_cnt, 0, (size_t)N * sizeof(int), stream);
    hist_kernel<<<(E + 255) / 256, blk, 0, stream>>>(dst, csr_cnt, E);
    scan_kernel<<<1, 1024, 0, stream>>>(csr_cnt, csr_off, csr_cur, N);
    scatter_kernel<<<(E + 255) / 256, blk, 0, stream>>>(src, dst, csr_cur, esrc, E);

    // K1: y = relu(xb @ Wp^T + bp)
    mfma_gemm<128, 1><<<(N / 128) * 1, blk, 0, stream>>>(
        bufX, 256, Wp_b, bp, y, 128);

    // pool: bufX[:,128:256] = segment_max(y[src]) by dst
    pool_kernel<<<N / 4, blk, 0, stream>>>((const unsigned int*)y, csr_off, esrc, bufX);

    // K4: h = leaky(concat(xb,pooled) @ concat_k(Ws,Wn)^T + bn)
    mfma_gemm<256, 2><<<(N / 128) * 1, blk, 0, stream>>>(
        bufX, 256, Wcat, bn, hbuf, 128);

    // K5: h2 = leaky(h @ W1^T + b1)
    mfma_gemm<128, 2><<<(N / 128) * 2, blk, 0, stream>>>(
        hbuf, 128, W1_b, b1, h2, 256);

    // head: out = sigmoid(h2 @ W2^T + b2)
    head_mfma<<<N / 64, blk, 0, stream>>>(h2, W2_b, b2, out);
}

// Round 4
// 381.778 us; speedup vs baseline: 4.3653x; 1.0175x over previous
//
#include <hip/hip_runtime.h>
#include <cstdint>
#include <cstddef>

typedef __attribute__((ext_vector_type(8))) __bf16 bf16x8;
typedef __attribute__((ext_vector_type(4))) float f32x4;

#define NOPAIR 0xFFFFFFFFu

static __device__ __forceinline__ unsigned short f2b(float f) {
    union { float f; unsigned int u; } v; v.f = f;
    unsigned int u = v.u;
    unsigned int r = (u + 0x7fffu + ((u >> 16) & 1u)) >> 16;  // RNE
    return (unsigned short)r;
}

// ---------------------------------------------------------------------------
// MFMA GEMM: C[M,Ncols](bf16) = act(A[M,K](bf16, strideA) @ W[Ncols,K](bf16)^T + bias)
// Block 256 thr = 4 waves (2x2), wave does 64x64 via 4x4 tiles of 16x16x32.
// A: m=lane&15, k=quad*8+j; B: n=lane&15, k=quad*8+j; C/D: col=lane&15, row=quad*4+reg.
// ACT: 1=relu, 2=leaky_relu(0.01)
// ---------------------------------------------------------------------------
template<int K, int ACT>
__global__ __launch_bounds__(256) void mfma_gemm(
    const unsigned short* __restrict__ A, int strideA,
    const unsigned short* __restrict__ W,
    const float* __restrict__ bias,
    unsigned short* __restrict__ C, int Ncols)
{
    const int nt = Ncols >> 7;
    const int bm = (int)blockIdx.x / nt, bn = (int)blockIdx.x % nt;
    const int w  = threadIdx.x >> 6;
    const int wm = w & 1, wn = w >> 1;
    const int l  = threadIdx.x & 63;
    const int lr = l & 15, quad = l >> 4;
    const int m0 = bm * 128 + wm * 64;
    const int n0 = bn * 128 + wn * 64;

    f32x4 acc[4][4];
#pragma unroll
    for (int i = 0; i < 4; i++)
#pragma unroll
        for (int j = 0; j < 4; j++) acc[i][j] = (f32x4){0.f, 0.f, 0.f, 0.f};

    const unsigned short* Ap = A + (size_t)(m0 + lr) * strideA + quad * 8;
    const unsigned short* Bp = W + (size_t)(n0 + lr) * K + quad * 8;

    for (int ks = 0; ks < K / 32; ks++) {
        bf16x8 af[4], bf[4];
#pragma unroll
        for (int i = 0; i < 4; i++)
            af[i] = *(const bf16x8*)(Ap + (size_t)i * 16 * strideA + ks * 32);
#pragma unroll
        for (int i = 0; i < 4; i++)
            bf[i] = *(const bf16x8*)(Bp + (size_t)i * 16 * K + ks * 32);
#pragma unroll
        for (int mi = 0; mi < 4; mi++)
#pragma unroll
            for (int ni = 0; ni < 4; ni++)
                acc[mi][ni] = __builtin_amdgcn_mfma_f32_16x16x32_bf16(
                    af[mi], bf[ni], acc[mi][ni], 0, 0, 0);
    }

#pragma unroll
    for (int ni = 0; ni < 4; ni++) {
        const int col = n0 + ni * 16 + lr;
        const float bv = bias[col];
#pragma unroll
        for (int mi = 0; mi < 4; mi++) {
#pragma unroll
            for (int r = 0; r < 4; r++) {
                const int row = m0 + mi * 16 + quad * 4 + r;
                float v = acc[mi][ni][r] + bv;
                if (ACT == 1) v = v > 0.f ? v : 0.f;
                if (ACT == 2) v = v > 0.f ? v : 0.01f * v;
                C[(size_t)row * Ncols + col] = f2b(v);
            }
        }
    }
}

// ---------------------------------------------------------------------------
// Head: out[N,16](fp32) = sigmoid(H[N,256](bf16) @ W2[16,256](bf16)^T + b2).
// ---------------------------------------------------------------------------
__global__ __launch_bounds__(256) void head_mfma(
    const unsigned short* __restrict__ H, const unsigned short* __restrict__ W2b,
    const float* __restrict__ b2, float* __restrict__ out)
{
    const int wave = (int)(blockIdx.x * 4) + (threadIdx.x >> 6);
    const int l = threadIdx.x & 63;
    const int lr = l & 15, quad = l >> 4;
    const int m0 = wave * 16;
    f32x4 acc = (f32x4){0.f, 0.f, 0.f, 0.f};
#pragma unroll
    for (int ks = 0; ks < 8; ks++) {
        bf16x8 a = *(const bf16x8*)(H + (size_t)(m0 + lr) * 256 + ks * 32 + quad * 8);
        bf16x8 b = *(const bf16x8*)(W2b + (size_t)lr * 256 + ks * 32 + quad * 8);
        acc = __builtin_amdgcn_mfma_f32_16x16x32_bf16(a, b, acc, 0, 0, 0);
    }
    const float bv = b2[lr];
#pragma unroll
    for (int r = 0; r < 4; r++) {
        const int row = m0 + quad * 4 + r;
        float v = acc[r] + bv;
        out[(size_t)row * 16 + lr] = 1.f / (1.f + __expf(-v));
    }
}

// ---------------------------------------------------------------------------
// Conversions
// ---------------------------------------------------------------------------
__global__ __launch_bounds__(256) void conv_x_kernel(
    const float* __restrict__ x, unsigned short* __restrict__ bufX, int total)
{
    int t = blockIdx.x * 256 + threadIdx.x;
    if (t >= total) return;
    int row = t >> 5, seg = t & 31;
    float4 v = *(const float4*)(x + (size_t)row * 128 + seg * 4);
    ushort4 o;
    o.x = f2b(v.x); o.y = f2b(v.y); o.z = f2b(v.z); o.w = f2b(v.w);
    *(ushort4*)(bufX + (size_t)row * 256 + seg * 4) = o;
}

__global__ __launch_bounds__(256) void conv_w_kernel(
    const float* __restrict__ Wp, const float* __restrict__ Ws,
    const float* __restrict__ Wn, const float* __restrict__ W1,
    const float* __restrict__ W2,
    unsigned short* __restrict__ Wp_b, unsigned short* __restrict__ Wcat,
    unsigned short* __restrict__ W1_b, unsigned short* __restrict__ W2_b)
{
    int i = blockIdx.x * 256 + threadIdx.x;
    if (i < 16384) {
        Wp_b[i] = f2b(Wp[i]);
    } else if (i < 49152) {
        int j = i - 16384; int o = j >> 8, k = j & 255;
        Wcat[j] = f2b(k < 128 ? Ws[o * 128 + k] : Wn[o * 128 + (k - 128)]);
    } else if (i < 81920) {
        W1_b[i - 49152] = f2b(W1[i - 49152]);
    } else if (i < 86016) {
        W2_b[i - 81920] = f2b(W2[i - 81920]);
    }
}

// ---------------------------------------------------------------------------
// Bucketed segment-max pipeline. Bucket = dst >> 7 (512 buckets x 128 nodes).
// ---------------------------------------------------------------------------
__global__ __launch_bounds__(256) void bucket_count(
    const int* __restrict__ dst, int* __restrict__ bcnt, int E)
{
    __shared__ int h[512];
    for (int i = threadIdx.x; i < 512; i += 256) h[i] = 0;
    __syncthreads();
    int base = blockIdx.x * 4096;
#pragma unroll
    for (int i = 0; i < 16; i++) {
        int e = base + i * 256 + threadIdx.x;
        if (e < E) atomicAdd(&h[((unsigned)dst[e]) >> 7], 1);
    }
    __syncthreads();
    for (int i = threadIdx.x; i < 512; i += 256)
        if (h[i]) atomicAdd(&bcnt[i], h[i]);
}

__global__ __launch_bounds__(512) void bucket_scan(
    const int* __restrict__ bcnt, int* __restrict__ boff, int* __restrict__ bcur)
{
    __shared__ int s[512];
    int t = threadIdx.x;
    s[t] = bcnt[t];
    __syncthreads();
    for (int d = 1; d < 512; d <<= 1) {
        int add = (t >= d) ? s[t - d] : 0;
        __syncthreads();
        s[t] += add;
        __syncthreads();
    }
    int ex = (t == 0) ? 0 : s[t - 1];
    boff[t] = ex; bcur[t] = ex;
    if (t == 511) boff[512] = s[511];
}

// Two-level scatter: block reserves a contiguous chunk per touched bucket,
// then writes packed pairs (src<<7 | dst&127) into its chunk (~32B runs).
__global__ __launch_bounds__(256) void bucket_scatter(
    const int* __restrict__ src, const int* __restrict__ dst,
    int* __restrict__ bcur, unsigned int* __restrict__ pairs, int E)
{
    __shared__ int h[512];
    __shared__ int base_l[512];
    __shared__ int cnt[512];
    for (int i = threadIdx.x; i < 512; i += 256) { h[i] = 0; cnt[i] = 0; }
    __syncthreads();
    int base = blockIdx.x * 4096;
    int d_r[16], s_r[16];
#pragma unroll
    for (int i = 0; i < 16; i++) {
        int e = base + i * 256 + threadIdx.x;
        if (e < E) {
            d_r[i] = dst[e]; s_r[i] = src[e];
            atomicAdd(&h[((unsigned)d_r[i]) >> 7], 1);
        } else d_r[i] = -1;
    }
    __syncthreads();
    for (int i = threadIdx.x; i < 512; i += 256)
        base_l[i] = h[i] ? atomicAdd(&bcur[i], h[i]) : 0;
    __syncthreads();
#pragma unroll
    for (int i = 0; i < 16; i++) {
        if (d_r[i] >= 0) {
            int b = ((unsigned)d_r[i]) >> 7;
            int pos = base_l[b] + atomicAdd(&cnt[b], 1);
            pairs[pos] = ((unsigned)s_r[i] << 7) | ((unsigned)d_r[i] & 127u);
        }
    }
}

// Fused pool: block b owns dst nodes [b*128, b*128+128). Pooled maxima live in
// LDS fp32 (even/odd feature split -> stride-1 lanes, conflict-free). Waves
// broadcast pairs via shfl, gather y rows (4B/lane = 256B coalesced), LDS
// atomicMax (y>=0, int-monotone). Epilogue packs bf16 into bufX[:,128:256].
__global__ __launch_bounds__(256) void bucket_pool(
    const unsigned int* __restrict__ yu, const int* __restrict__ boff,
    const unsigned int* __restrict__ pairs, unsigned short* __restrict__ bufX)
{
    __shared__ float poolE[128 * 64];
    __shared__ float poolO[128 * 64];
    const int b = blockIdx.x;
    const int tid = threadIdx.x;
    const int lane = tid & 63;
    for (int i = tid; i < 128 * 64; i += 256) { poolE[i] = 0.f; poolO[i] = 0.f; }
    __syncthreads();

    const int beg = boff[b], end = boff[b + 1];
    for (int g0 = beg; g0 < end; g0 += 256) {
        int idx = g0 + tid;
        unsigned int p = (idx < end) ? pairs[idx] : NOPAIR;
#pragma unroll
        for (int k0 = 0; k0 < 64; k0 += 8) {
            unsigned int pw[8]; float ve[8], vo[8];
#pragma unroll
            for (int j = 0; j < 8; j++) pw[j] = (unsigned int)__shfl((int)p, k0 + j);
#pragma unroll
            for (int j = 0; j < 8; j++) {
                if (pw[j] != NOPAIR) {
                    unsigned int v = yu[(size_t)(pw[j] >> 7) * 64 + lane];
                    ve[j] = __uint_as_float(v << 16);
                    vo[j] = __uint_as_float(v & 0xffff0000u);
                }
            }
#pragma unroll
            for (int j = 0; j < 8; j++) {
                if (pw[j] != NOPAIR) {
                    int d = pw[j] & 127;
                    atomicMax((int*)&poolE[d * 64 + lane], __float_as_int(ve[j]));
                    atomicMax((int*)&poolO[d * 64 + lane], __float_as_int(vo[j]));
                }
            }
        }
    }
    __syncthreads();

    for (int i = tid; i < 128 * 64; i += 256) {
        int row = i >> 6, w = i & 63;
        unsigned int lo = __float_as_uint(poolE[row * 64 + w]) >> 16;   // exact bf16
        unsigned int hi = __float_as_uint(poolO[row * 64 + w]) & 0xffff0000u;
        ((unsigned int*)bufX)[(size_t)(b * 128 + row) * 128 + 64 + w] = lo | hi;
    }
}

// ---------------------------------------------------------------------------
extern "C" void kernel_launch(void* const* d_in, const int* in_sizes, int n_in,
                              void* d_out, int out_size, void* d_ws, size_t ws_size,
                              hipStream_t stream)
{
    const float* x  = (const float*)d_in[0];
    const float* Wp = (const float*)d_in[1];
    const float* bp = (const float*)d_in[2];
    const float* Ws = (const float*)d_in[3];
    const float* Wn = (const float*)d_in[4];
    const float* bn = (const float*)d_in[5];
    const float* W1 = (const float*)d_in[6];
    const float* b1 = (const float*)d_in[7];
    const float* W2 = (const float*)d_in[8];
    const float* b2 = (const float*)d_in[9];
    const int* src  = (const int*)d_in[10];
    const int* dst  = (const int*)d_in[11];
    float* out = (float*)d_out;

    const int N = in_sizes[0] / 128;   // 65536
    const int E = in_sizes[10];        // 1048576

    // ws layout:
    //   [ 0,32M)  bufX : [N,256] bf16 — cols 0:128 = xb, cols 128:256 = pooled
    //   [32M,48M) y    : [N,128] bf16
    //   [48M,64M) hbuf : [N,128] bf16
    //   [64M,96M) h2   : [N,256] bf16
    //   [96M,..)  bf16 weights, bucket arrays, pairs (4MB)
    unsigned short* bufX = (unsigned short*)d_ws;
    unsigned short* y    = (unsigned short*)((char*)d_ws + (size_t)32 * 1024 * 1024);
    unsigned short* hbuf = (unsigned short*)((char*)d_ws + (size_t)48 * 1024 * 1024);
    unsigned short* h2   = (unsigned short*)((char*)d_ws + (size_t)64 * 1024 * 1024);

    unsigned short* Wp_b = (unsigned short*)((char*)d_ws + (size_t)96 * 1024 * 1024);
    unsigned short* Wcat = Wp_b + 16384;     // 128 x 256
    unsigned short* W1_b = Wcat + 32768;     // 256 x 128
    unsigned short* W2_b = W1_b + 32768;     // 16 x 256
    int* bcnt = (int*)(W2_b + 4096);         // 512
    int* boff = bcnt + 512;                  // 513
    int* bcur = boff + 513 + 1;              // 512 (aligned)
    unsigned int* pairs = (unsigned int*)(bcur + 512);   // E

    dim3 blk(256);

    // conversions (independent)
    conv_w_kernel<<<(86016 + 255) / 256, blk, 0, stream>>>(
        Wp, Ws, Wn, W1, W2, Wp_b, Wcat, W1_b, W2_b);
    conv_x_kernel<<<(N * 32 + 255) / 256, blk, 0, stream>>>(x, bufX, N * 32);

    // bucket build
    hipMemsetAsync(bcnt, 0, 512 * sizeof(int), stream);
    const int ebks = (E + 4095) / 4096;
    bucket_count<<<ebks, blk, 0, stream>>>(dst, bcnt, E);
    bucket_scan<<<1, 512, 0, stream>>>(bcnt, boff, bcur);
    bucket_scatter<<<ebks, blk, 0, stream>>>(src, dst, bcur, pairs, E);

    // K1: y = relu(xb @ Wp^T + bp)
    mfma_gemm<128, 1><<<(N / 128) * 1, blk, 0, stream>>>(
        bufX, 256, Wp_b, bp, y, 128);

    // fused pool: bufX[:,128:256] = segment_max(y[src]) by dst
    bucket_pool<<<512, blk, 0, stream>>>((const unsigned int*)y, boff, pairs, bufX);

    // K4: h = leaky(concat(xb,pooled) @ concat_k(Ws,Wn)^T + bn)
    mfma_gemm<256, 2><<<(N / 128) * 1, blk, 0, stream>>>(
        bufX, 256, Wcat, bn, hbuf, 128);

    // K5: h2 = leaky(h @ W1^T + b1)
    mfma_gemm<128, 2><<<(N / 128) * 2, blk, 0, stream>>>(
        hbuf, 128, W1_b, b1, h2, 256);

    // head: out = sigmoid(h2 @ W2^T + b2)
    head_mfma<<<N / 64, blk, 0, stream>>>(h2, W2_b, b2, out);
}

// Round 5
// 238.239 us; speedup vs baseline: 6.9954x; 1.6025x over previous
//
#include <hip/hip_runtime.h>
#include <cstdint>
#include <cstddef>

typedef __attribute__((ext_vector_type(8))) __bf16 bf16x8;
typedef __attribute__((ext_vector_type(4))) float f32x4;

static __device__ __forceinline__ unsigned short f2b(float f) {
    union { float f; unsigned int u; } v; v.f = f;
    unsigned int u = v.u;
    unsigned int r = (u + 0x7fffu + ((u >> 16) & 1u)) >> 16;  // RNE
    return (unsigned short)r;
}

// ---------------------------------------------------------------------------
// MFMA GEMM: C[M,Ncols](bf16) = act(A[M,K](bf16, strideA) @ W[Ncols,K](bf16)^T + bias)
// Block 256 thr = 4 waves (2x2), wave does 64x64 via 4x4 tiles of 16x16x32.
// A: m=lane&15, k=quad*8+j; B: n=lane&15, k=quad*8+j; C/D: col=lane&15, row=quad*4+reg.
// ACT: 1=relu, 2=leaky_relu(0.01)
// ---------------------------------------------------------------------------
template<int K, int ACT>
__global__ __launch_bounds__(256) void mfma_gemm(
    const unsigned short* __restrict__ A, int strideA,
    const unsigned short* __restrict__ W,
    const float* __restrict__ bias,
    unsigned short* __restrict__ C, int Ncols)
{
    const int nt = Ncols >> 7;
    const int bm = (int)blockIdx.x / nt, bn = (int)blockIdx.x % nt;
    const int w  = threadIdx.x >> 6;
    const int wm = w & 1, wn = w >> 1;
    const int l  = threadIdx.x & 63;
    const int lr = l & 15, quad = l >> 4;
    const int m0 = bm * 128 + wm * 64;
    const int n0 = bn * 128 + wn * 64;

    f32x4 acc[4][4];
#pragma unroll
    for (int i = 0; i < 4; i++)
#pragma unroll
        for (int j = 0; j < 4; j++) acc[i][j] = (f32x4){0.f, 0.f, 0.f, 0.f};

    const unsigned short* Ap = A + (size_t)(m0 + lr) * strideA + quad * 8;
    const unsigned short* Bp = W + (size_t)(n0 + lr) * K + quad * 8;

    for (int ks = 0; ks < K / 32; ks++) {
        bf16x8 af[4], bf[4];
#pragma unroll
        for (int i = 0; i < 4; i++)
            af[i] = *(const bf16x8*)(Ap + (size_t)i * 16 * strideA + ks * 32);
#pragma unroll
        for (int i = 0; i < 4; i++)
            bf[i] = *(const bf16x8*)(Bp + (size_t)i * 16 * K + ks * 32);
#pragma unroll
        for (int mi = 0; mi < 4; mi++)
#pragma unroll
            for (int ni = 0; ni < 4; ni++)
                acc[mi][ni] = __builtin_amdgcn_mfma_f32_16x16x32_bf16(
                    af[mi], bf[ni], acc[mi][ni], 0, 0, 0);
    }

#pragma unroll
    for (int ni = 0; ni < 4; ni++) {
        const int col = n0 + ni * 16 + lr;
        const float bv = bias[col];
#pragma unroll
        for (int mi = 0; mi < 4; mi++) {
#pragma unroll
            for (int r = 0; r < 4; r++) {
                const int row = m0 + mi * 16 + quad * 4 + r;
                float v = acc[mi][ni][r] + bv;
                if (ACT == 1) v = v > 0.f ? v : 0.f;
                if (ACT == 2) v = v > 0.f ? v : 0.01f * v;
                C[(size_t)row * Ncols + col] = f2b(v);
            }
        }
    }
}

// ---------------------------------------------------------------------------
// Head: out[N,16](fp32) = sigmoid(H[N,256](bf16) @ W2[16,256](bf16)^T + b2).
// ---------------------------------------------------------------------------
__global__ __launch_bounds__(256) void head_mfma(
    const unsigned short* __restrict__ H, const unsigned short* __restrict__ W2b,
    const float* __restrict__ b2, float* __restrict__ out)
{
    const int wave = (int)(blockIdx.x * 4) + (threadIdx.x >> 6);
    const int l = threadIdx.x & 63;
    const int lr = l & 15, quad = l >> 4;
    const int m0 = wave * 16;
    f32x4 acc = (f32x4){0.f, 0.f, 0.f, 0.f};
#pragma unroll
    for (int ks = 0; ks < 8; ks++) {
        bf16x8 a = *(const bf16x8*)(H + (size_t)(m0 + lr) * 256 + ks * 32 + quad * 8);
        bf16x8 b = *(const bf16x8*)(W2b + (size_t)lr * 256 + ks * 32 + quad * 8);
        acc = __builtin_amdgcn_mfma_f32_16x16x32_bf16(a, b, acc, 0, 0, 0);
    }
    const float bv = b2[lr];
#pragma unroll
    for (int r = 0; r < 4; r++) {
        const int row = m0 + quad * 4 + r;
        float v = acc[r] + bv;
        out[(size_t)row * 16 + lr] = 1.f / (1.f + __expf(-v));
    }
}

// ---------------------------------------------------------------------------
// Conversions
// ---------------------------------------------------------------------------
__global__ __launch_bounds__(256) void conv_x_kernel(
    const float* __restrict__ x, unsigned short* __restrict__ bufX, int total)
{
    int t = blockIdx.x * 256 + threadIdx.x;
    if (t >= total) return;
    int row = t >> 5, seg = t & 31;
    float4 v = *(const float4*)(x + (size_t)row * 128 + seg * 4);
    ushort4 o;
    o.x = f2b(v.x); o.y = f2b(v.y); o.z = f2b(v.z); o.w = f2b(v.w);
    *(ushort4*)(bufX + (size_t)row * 256 + seg * 4) = o;
}

__global__ __launch_bounds__(256) void conv_w_kernel(
    const float* __restrict__ Wp, const float* __restrict__ Ws,
    const float* __restrict__ Wn, const float* __restrict__ W1,
    const float* __restrict__ W2,
    unsigned short* __restrict__ Wp_b, unsigned short* __restrict__ Wcat,
    unsigned short* __restrict__ W1_b, unsigned short* __restrict__ W2_b)
{
    int i = blockIdx.x * 256 + threadIdx.x;
    if (i < 16384) {
        Wp_b[i] = f2b(Wp[i]);
    } else if (i < 49152) {
        int j = i - 16384; int o = j >> 8, k = j & 255;
        Wcat[j] = f2b(k < 128 ? Ws[o * 128 + k] : Wn[o * 128 + (k - 128)]);
    } else if (i < 81920) {
        W1_b[i - 49152] = f2b(W1[i - 49152]);
    } else if (i < 86016) {
        W2_b[i - 81920] = f2b(W2[i - 81920]);
    }
}

// ---------------------------------------------------------------------------
// Bucketed pipeline: bucket = dst >> 6 (1024 buckets x 64 nodes).
// Pairs packed as (src << 6) | (dst & 63).
// ---------------------------------------------------------------------------
__global__ __launch_bounds__(256) void bucket_count(
    const int* __restrict__ dst, int* __restrict__ bcnt, int E)
{
    __shared__ int h[1024];
    for (int i = threadIdx.x; i < 1024; i += 256) h[i] = 0;
    __syncthreads();
    int base = blockIdx.x * 4096;
#pragma unroll
    for (int i = 0; i < 16; i++) {
        int e = base + i * 256 + threadIdx.x;
        if (e < E) atomicAdd(&h[((unsigned)dst[e]) >> 6], 1);
    }
    __syncthreads();
    for (int i = threadIdx.x; i < 1024; i += 256)
        if (h[i]) atomicAdd(&bcnt[i], h[i]);
}

__global__ __launch_bounds__(1024) void bucket_scan(
    const int* __restrict__ bcnt, int* __restrict__ boff, int* __restrict__ bcur)
{
    __shared__ int s[1024];
    int t = threadIdx.x;
    s[t] = bcnt[t];
    __syncthreads();
    for (int d = 1; d < 1024; d <<= 1) {
        int add = (t >= d) ? s[t - d] : 0;
        __syncthreads();
        s[t] += add;
        __syncthreads();
    }
    int ex = (t == 0) ? 0 : s[t - 1];
    boff[t] = ex; bcur[t] = ex;
    if (t == 1023) boff[1024] = s[1023];
}

// Two-level scatter: block reserves contiguous chunks per touched bucket,
// writes packed pairs into its chunks (~16B runs).
__global__ __launch_bounds__(256) void bucket_scatter(
    const int* __restrict__ src, const int* __restrict__ dst,
    int* __restrict__ bcur, unsigned int* __restrict__ pairs, int E)
{
    __shared__ int h[1024];
    __shared__ int base_l[1024];
    __shared__ int cnt[1024];
    for (int i = threadIdx.x; i < 1024; i += 256) { h[i] = 0; cnt[i] = 0; }
    __syncthreads();
    int base = blockIdx.x * 4096;
    int d_r[16], s_r[16];
#pragma unroll
    for (int i = 0; i < 16; i++) {
        int e = base + i * 256 + threadIdx.x;
        if (e < E) {
            d_r[i] = dst[e]; s_r[i] = src[e];
            atomicAdd(&h[((unsigned)d_r[i]) >> 6], 1);
        } else d_r[i] = -1;
    }
    __syncthreads();
    for (int i = threadIdx.x; i < 1024; i += 256)
        base_l[i] = h[i] ? atomicAdd(&bcur[i], h[i]) : 0;
    __syncthreads();
#pragma unroll
    for (int i = 0; i < 16; i++) {
        if (d_r[i] >= 0) {
            int b = ((unsigned)d_r[i]) >> 6;
            int pos = base_l[b] + atomicAdd(&cnt[b], 1);
            pairs[pos] = ((unsigned)s_r[i] << 6) | ((unsigned)d_r[i] & 63u);
        }
    }
}

// Pool: block = bucket of 64 dst nodes (~1024 pairs). Counting-sort the
// bucket's pairs by dst into an LDS src-list (6 KB), then each wave owns 16
// nodes: per node, gather y rows (4B/lane coalesced) with 8-deep batches,
// register fmax (lane = 2 feats). Tail edges clamp-duplicate the last edge
// (max is idempotent) so every batch is full-depth ILP. Direct bf16 store
// into bufX[:,128:256]; init-0 covers isolated nodes (y >= 0).
__global__ __launch_bounds__(256) void bucket_pool2(
    const unsigned int* __restrict__ yu, const int* __restrict__ boff,
    const unsigned int* __restrict__ pairs, unsigned short* __restrict__ bufX)
{
    __shared__ unsigned short ldsSrc[3072];
    __shared__ int bin[64], offl[64], cnt2[64];
    const int b = blockIdx.x;
    const int tid = threadIdx.x;
    if (tid < 64) { bin[tid] = 0; cnt2[tid] = 0; }
    __syncthreads();
    const int beg = boff[b];
    const int nb = boff[b + 1] - beg;

    for (int i = tid; i < nb; i += 256)
        atomicAdd(&bin[pairs[beg + i] & 63u], 1);
    __syncthreads();
    if (tid == 0) {
        int run = 0;
        for (int i = 0; i < 64; i++) { offl[i] = run; run += bin[i]; }
    }
    __syncthreads();
    for (int i = tid; i < nb; i += 256) {
        unsigned int p = pairs[beg + i];
        int d = p & 63u;
        int slot = offl[d] + atomicAdd(&cnt2[d], 1);
        ldsSrc[slot] = (unsigned short)(p >> 6);
    }
    __syncthreads();

    const int w = tid >> 6, lane = tid & 63;
    for (int ni = 0; ni < 16; ni++) {
        const int n = w * 16 + ni;
        const int e0 = offl[n], cnt = bin[n];
        float ax = 0.f, ay = 0.f;
        for (int e = 0; e < cnt; e += 8) {
            int s[8]; unsigned int v[8];
#pragma unroll
            for (int j = 0; j < 8; j++) {
                int idx = e + j; idx = idx < cnt ? idx : cnt - 1;   // clamp: dup last
                s[j] = ldsSrc[e0 + idx];
            }
#pragma unroll
            for (int j = 0; j < 8; j++) v[j] = yu[(size_t)s[j] * 64 + lane];
#pragma unroll
            for (int j = 0; j < 8; j++) {
                ax = fmaxf(ax, __uint_as_float(v[j] << 16));
                ay = fmaxf(ay, __uint_as_float(v[j] & 0xffff0000u));
            }
        }
        unsigned int packed = (__float_as_uint(ax) >> 16) | (__float_as_uint(ay) & 0xffff0000u);
        ((unsigned int*)bufX)[(size_t)(b * 64 + n) * 128 + 64 + lane] = packed;
    }
}

// ---------------------------------------------------------------------------
extern "C" void kernel_launch(void* const* d_in, const int* in_sizes, int n_in,
                              void* d_out, int out_size, void* d_ws, size_t ws_size,
                              hipStream_t stream)
{
    const float* x  = (const float*)d_in[0];
    const float* Wp = (const float*)d_in[1];
    const float* bp = (const float*)d_in[2];
    const float* Ws = (const float*)d_in[3];
    const float* Wn = (const float*)d_in[4];
    const float* bn = (const float*)d_in[5];
    const float* W1 = (const float*)d_in[6];
    const float* b1 = (const float*)d_in[7];
    const float* W2 = (const float*)d_in[8];
    const float* b2 = (const float*)d_in[9];
    const int* src  = (const int*)d_in[10];
    const int* dst  = (const int*)d_in[11];
    float* out = (float*)d_out;

    const int N = in_sizes[0] / 128;   // 65536
    const int E = in_sizes[10];        // 1048576

    // ws layout:
    //   [ 0,32M)  bufX : [N,256] bf16 — cols 0:128 = xb, cols 128:256 = pooled
    //   [32M,48M) y    : [N,128] bf16
    //   [48M,64M) hbuf : [N,128] bf16
    //   [64M,96M) h2   : [N,256] bf16
    //   [96M,..)  bf16 weights, bucket arrays, pairs (4MB)
    unsigned short* bufX = (unsigned short*)d_ws;
    unsigned short* y    = (unsigned short*)((char*)d_ws + (size_t)32 * 1024 * 1024);
    unsigned short* hbuf = (unsigned short*)((char*)d_ws + (size_t)48 * 1024 * 1024);
    unsigned short* h2   = (unsigned short*)((char*)d_ws + (size_t)64 * 1024 * 1024);

    unsigned short* Wp_b = (unsigned short*)((char*)d_ws + (size_t)96 * 1024 * 1024);
    unsigned short* Wcat = Wp_b + 16384;     // 128 x 256
    unsigned short* W1_b = Wcat + 32768;     // 256 x 128
    unsigned short* W2_b = W1_b + 32768;     // 16 x 256
    int* bcnt = (int*)(W2_b + 4096);         // 1024
    int* boff = bcnt + 1024;                 // 1025
    int* bcur = boff + 1025 + 3;             // 1024 (16B aligned)
    unsigned int* pairs = (unsigned int*)(bcur + 1024);   // E

    dim3 blk(256);

    // conversions (independent)
    conv_w_kernel<<<(86016 + 255) / 256, blk, 0, stream>>>(
        Wp, Ws, Wn, W1, W2, Wp_b, Wcat, W1_b, W2_b);
    conv_x_kernel<<<(N * 32 + 255) / 256, blk, 0, stream>>>(x, bufX, N * 32);

    // bucket build
    hipMemsetAsync(bcnt, 0, 1024 * sizeof(int), stream);
    const int ebks = (E + 4095) / 4096;
    bucket_count<<<ebks, blk, 0, stream>>>(dst, bcnt, E);
    bucket_scan<<<1, 1024, 0, stream>>>(bcnt, boff, bcur);
    bucket_scatter<<<ebks, blk, 0, stream>>>(src, dst, bcur, pairs, E);

    // K1: y = relu(xb @ Wp^T + bp)
    mfma_gemm<128, 1><<<(N / 128) * 1, blk, 0, stream>>>(
        bufX, 256, Wp_b, bp, y, 128);

    // pool: bufX[:,128:256] = segment_max(y[src]) by dst
    bucket_pool2<<<1024, blk, 0, stream>>>((const unsigned int*)y, boff, pairs, bufX);

    // K4: h = leaky(concat(xb,pooled) @ concat_k(Ws,Wn)^T + bn)
    mfma_gemm<256, 2><<<(N / 128) * 1, blk, 0, stream>>>(
        bufX, 256, Wcat, bn, hbuf, 128);

    // K5: h2 = leaky(h @ W1^T + b1)
    mfma_gemm<128, 2><<<(N / 128) * 2, blk, 0, stream>>>(
        hbuf, 128, W1_b, b1, h2, 256);

    // head: out = sigmoid(h2 @ W2^T + b2)
    head_mfma<<<N / 64, blk, 0, stream>>>(h2, W2_b, b2, out);
}